// Round 9
// baseline (168.813 us; speedup 1.0000x reference)
//
#include <hip/hip_runtime.h>
#include <hip/hip_bf16.h>
#include <math.h>

// AttentionDownSample: fm [8,128,256,256] f32, Wq/Wk [32,128] f32
// out [8,128,128,128] f32.
//
// r9 = r8 (register-stash, read-fm-once) + spill fix.
// r8 counters: FETCH dropped to 264 MB (read-once works) but WRITE blew up
// 67->218 MB with VGPR_Count=64: the 64-reg bf16x2 stash + qa[32] (~116 regs
// needed) was spilled to scratch because the allocator targeted 8 waves/EU
// (LDS allowed 8 blocks/CU). Fix: amdgpu_waves_per_eu(4,4) pins exactly
// 4 waves/EU -> 128-VGPR budget -> stash stays in registers.
//
// Decomposition per position (h,w):  u[c] = v0+v1+v2+v3 (window sum)
//   Q[r]    = sum_c WqT'[c][r] * u[c]       (WqT' has 0.25/sqrt(32) folded)
//   t[c]    = sum_r Q[r] * WkT[c][r]
//   logit_s = sum_c t[c] * v_s[c]
//   out[c]  = sum_s softmax(logit)_s * v_s[c]
//
// Block = 256 thr = 64 positions x 4 channel groups (32 ch each, wave-uniform
// group -> weights stay SMEM s_load). Grid = 8b x 128h x 2wt = 2048.
// LDS: Qpart[2][32][64] 16 KB (tree reduce) + lbuf[4][64][4] 4 KB = 20 KB.
// All stash loops fully unrolled (runtime-indexed reg arrays -> scratch).

typedef unsigned int uint32;

__device__ __forceinline__ uint32 pack2(float x, float y) {
  union { __hip_bfloat162 h; uint32 u; } cvt;
  cvt.h = __float22bfloat162_rn(make_float2(x, y));
  return cvt.u;
}
__device__ __forceinline__ float2 unpack2(uint32 u) {
  float2 r;
  r.x = __uint_as_float(u << 16);
  r.y = __uint_as_float(u & 0xffff0000u);
  return r;
}

__global__ __launch_bounds__(256) void wt_kernel(const float* __restrict__ Wq,
                                                 const float* __restrict__ Wk,
                                                 float* __restrict__ ws) {
  int t = blockIdx.x * 256 + threadIdx.x;  // 4096 threads, one (c,r) each
  if (t < 4096) {
    int c = t >> 5, r = t & 31;
    ws[c * 32 + r]        = Wq[r * 128 + c] * (0.25f / sqrtf(32.0f));
    ws[4096 + c * 32 + r] = Wk[r * 128 + c];
  }
}

__global__ __launch_bounds__(256)
__attribute__((amdgpu_waves_per_eu(4, 4)))
void attn_main(const float* __restrict__ fm,
               const float* __restrict__ ws,
               float* __restrict__ out) {
  __shared__ float Qpart[2 * 32 * 64];  // [pair][r][p] 16 KB (tree reduce)
  __shared__ float lbuf[4 * 64 * 4];    // [grp][p][s]   4 KB; attn in [0]

  const int tid = threadIdx.x;
  const int p   = tid & 63;                                   // position
  const int grp = __builtin_amdgcn_readfirstlane(tid >> 6);   // 0..3

  const int blk = blockIdx.x;           // 2048 = 8 b * 128 h * 2 wh
  const int w0  = (blk & 1) * 64;
  const int h   = (blk >> 1) & 127;
  const int b   = blk >> 8;
  const int cb  = grp * 32;             // this group's channel base

  const float* gbase = fm + ((size_t)(b * 128 + cb) * 65536) +
                       (size_t)(2 * h) * 256 + 2 * (w0 + p);
  const float* wq = ws + cb * 32;          // WqT'[c][r], r contiguous
  const float* wk = ws + 4096 + cb * 32;   // WkT[c][r]

  // ---- phase M: single streaming read of this thread's fm slice ----
  // 32 channels x (row0 pair, row1 pair) -> 64 packed bf16x2 registers.
  uint32 pka[32], pkb[32];
  {
    const float* g = gbase;
#pragma unroll
    for (int i = 0; i < 32; ++i) {
      const float2 va = *(const float2*)(g);        // row 2h:   v0,v1
      const float2 vb = *(const float2*)(g + 256);  // row 2h+1: v2,v3
      pka[i] = pack2(va.x, va.y);
      pkb[i] = pack2(vb.x, vb.y);
      g += 65536;
    }
  }

  // ---- pass 1: partial Q over this group's 32 channels (from stash) ----
  float qa[32];
#pragma unroll
  for (int r = 0; r < 32; ++r) qa[r] = 0.f;
#pragma unroll
  for (int i = 0; i < 32; ++i) {
    const float2 va = unpack2(pka[i]);
    const float2 vb = unpack2(pkb[i]);
    const float u = (va.x + va.y) + (vb.x + vb.y);
#pragma unroll
    for (int r = 0; r < 32; ++r)
      qa[r] = fmaf(wq[i * 32 + r], u, qa[r]);
  }

  // ---- tree-reduce Q across the 4 groups ([r][p]: 2 lanes/bank = free) ----
  if (grp >= 2) {
#pragma unroll
    for (int r = 0; r < 32; ++r) Qpart[(grp - 2) * 2048 + r * 64 + p] = qa[r];
  }
  __syncthreads();
  if (grp < 2) {
#pragma unroll
    for (int r = 0; r < 32; ++r) Qpart[grp * 2048 + r * 64 + p] += qa[r];
  }
  __syncthreads();
#pragma unroll
  for (int r = 0; r < 32; ++r)
    qa[r] = Qpart[r * 64 + p] + Qpart[2048 + r * 64 + p];

  // ---- pass 2: logits from stash (pure VALU + SMEM) ----
  float l0 = 0.f, l1 = 0.f, l2 = 0.f, l3 = 0.f;
#pragma unroll
  for (int i = 0; i < 32; ++i) {
    const float2 va = unpack2(pka[i]);
    const float2 vb = unpack2(pkb[i]);
    float t0 = 0.f, t1 = 0.f;
#pragma unroll
    for (int r = 0; r < 32; r += 2) {
      t0 = fmaf(qa[r + 0], wk[i * 32 + r + 0], t0);
      t1 = fmaf(qa[r + 1], wk[i * 32 + r + 1], t1);
    }
    const float tv = t0 + t1;
    l0 = fmaf(tv, va.x, l0);
    l1 = fmaf(tv, va.y, l1);
    l2 = fmaf(tv, vb.x, l2);
    l3 = fmaf(tv, vb.y, l3);
  }
  *(float4*)(lbuf + (grp * 64 + p) * 4) = make_float4(l0, l1, l2, l3);
  __syncthreads();

  // ---- softmax (group 0 combines all 4 groups, broadcasts via lbuf[0]) ----
  if (grp == 0) {
    const float4 o1 = *(const float4*)(lbuf + (64 + p) * 4);
    const float4 o2 = *(const float4*)(lbuf + (128 + p) * 4);
    const float4 o3 = *(const float4*)(lbuf + (192 + p) * 4);
    const float L0 = (l0 + o1.x) + (o2.x + o3.x);
    const float L1 = (l1 + o1.y) + (o2.y + o3.y);
    const float L2 = (l2 + o1.z) + (o2.z + o3.z);
    const float L3 = (l3 + o1.w) + (o2.w + o3.w);
    const float mx = fmaxf(fmaxf(L0, L1), fmaxf(L2, L3));
    const float e0 = __expf(L0 - mx), e1 = __expf(L1 - mx);
    const float e2 = __expf(L2 - mx), e3 = __expf(L3 - mx);
    const float inv = 1.0f / ((e0 + e1) + (e2 + e3));
    *(float4*)(lbuf + p * 4) =
        make_float4(e0 * inv, e1 * inv, e2 * inv, e3 * inv);
  }
  __syncthreads();
  const float4 at = *(const float4*)(lbuf + p * 4);

  // ---- pass 3: weighted window sum from stash -> out (plain stores) ----
  {
    float* op = out + ((size_t)(b * 128 + cb) * 16384) + h * 128 + w0 + p;
#pragma unroll
    for (int i = 0; i < 32; ++i) {
      const float2 va = unpack2(pka[i]);
      const float2 vb = unpack2(pkb[i]);
      op[(size_t)i * 16384] =
          fmaf(at.x, va.x, fmaf(at.y, va.y, fmaf(at.z, vb.x, at.w * vb.y)));
    }
  }
}

extern "C" void kernel_launch(void* const* d_in, const int* in_sizes, int n_in,
                              void* d_out, int out_size, void* d_ws, size_t ws_size,
                              hipStream_t stream) {
  const float* fm = (const float*)d_in[0];
  const float* Wq = (const float*)d_in[1];
  const float* Wk = (const float*)d_in[2];
  float* outp = (float*)d_out;
  float* ws = (float*)d_ws;

  wt_kernel<<<16, 256, 0, stream>>>(Wq, Wk, ws);
  attn_main<<<2048, 256, 0, stream>>>(fm, ws, outp);
}

// Round 10
// 138.263 us; speedup vs baseline: 1.2210x; 1.2210x over previous
//
#include <hip/hip_runtime.h>
#include <hip/hip_bf16.h>
#include <math.h>

// AttentionDownSample: fm [8,128,256,256] f32, Wq/Wk [32,128] f32
// out [8,128,128,128] f32.
//
// r10: register-stash (read-fm-once) with a register budget that FITS the
// allocator's LDS-driven occupancy target.
// r8/r9 lesson: with 20 KB LDS the heuristic targets 8 waves/EU -> 64 VGPRs
// and spills the stash (WRITE_SIZE 218-256 MB of scratch). Fix: 512 threads,
// 16 ch/thread (stash 32 regs + qa[32] -> ~78 peak) and LDS = 41 KB ->
// 3 blocks/CU -> 6 waves/EU -> 85-VGPR budget -> no spill, 75% occupancy.
//
// Per position (h,w):  u[c] = v0+v1+v2+v3 (window sum, from bf16 stash)
//   Q[r]    = sum_c WqT'[c][r] * u[c]       (WqT' has 0.25/sqrt(32) folded)
//   t[c]    = sum_r Q[r] * WkT[c][r]
//   logit_s = sum_c t[c] * v_s[c]
//   out[c]  = sum_s softmax(logit)_s * v_s[c]
//
// Block = 512 thr = 64 positions x 8 groups x 16 channels. Weights =
// wave-uniform s_load (SMEM); fm = vector global loads (vmcnt); LDS only in
// barrier-separated bursts (no DS inside hot loops -> no lgkm mixing stalls).
// Q reduced via 3-step tree: 8 -> 4 -> 2 -> broadcast.

typedef unsigned int uint32;

__device__ __forceinline__ uint32 pack2(float x, float y) {
  union { __hip_bfloat162 h; uint32 u; } cvt;
  cvt.h = __float22bfloat162_rn(make_float2(x, y));
  return cvt.u;
}
__device__ __forceinline__ float2 unpack2(uint32 u) {
  float2 r;
  r.x = __uint_as_float(u << 16);
  r.y = __uint_as_float(u & 0xffff0000u);
  return r;
}

__global__ __launch_bounds__(256) void wt_kernel(const float* __restrict__ Wq,
                                                 const float* __restrict__ Wk,
                                                 float* __restrict__ ws) {
  int t = blockIdx.x * 256 + threadIdx.x;  // 4096 threads, one (c,r) each
  if (t < 4096) {
    int c = t >> 5, r = t & 31;
    ws[c * 32 + r]        = Wq[r * 128 + c] * (0.25f / sqrtf(32.0f));
    ws[4096 + c * 32 + r] = Wk[r * 128 + c];
  }
}

__global__ __launch_bounds__(512)
void attn_main(const float* __restrict__ fm,
               const float* __restrict__ ws,
               float* __restrict__ out) {
  __shared__ float Qpart[4 * 32 * 64];  // [k][r][p] 32 KB (8->4->2 tree)
  __shared__ float lbuf[8 * 64 * 4];    // [g][p][s]  8 KB
  __shared__ float abuf[64 * 4];        // [p][s]     1 KB

  const int tid = threadIdx.x;
  const int p   = tid & 63;                                   // position
  const int g   = __builtin_amdgcn_readfirstlane(tid >> 6);   // group 0..7

  const int blk = blockIdx.x;           // 2048 = 8 b * 128 h * 2 wh
  const int w0  = (blk & 1) * 64;
  const int h   = (blk >> 1) & 127;
  const int b   = blk >> 8;
  const int cb  = g * 16;               // this group's channel base

  const float* gbase = fm + ((size_t)(b * 128 + cb) * 65536) +
                       (size_t)(2 * h) * 256 + 2 * (w0 + p);
  const float* wq = ws + cb * 32;          // WqT'[c][r], r contiguous
  const float* wk = ws + 4096 + cb * 32;   // WkT[c][r]

  // ---- phase M: single streaming read of this thread's fm slice ----
  // 16 channels x (row0 pair, row1 pair) -> 32 packed bf16x2 registers.
  uint32 pka[16], pkb[16];
  {
    const float* gp = gbase;
#pragma unroll
    for (int i = 0; i < 16; ++i) {
      const float2 va = *(const float2*)(gp);        // row 2h:   v0,v1
      const float2 vb = *(const float2*)(gp + 256);  // row 2h+1: v2,v3
      pka[i] = pack2(va.x, va.y);
      pkb[i] = pack2(vb.x, vb.y);
      gp += 65536;
    }
  }

  // ---- pass 1: partial Q over this group's 16 channels (from stash) ----
  float qa[32];
#pragma unroll
  for (int r = 0; r < 32; ++r) qa[r] = 0.f;
#pragma unroll
  for (int i = 0; i < 16; ++i) {
    const float2 va = unpack2(pka[i]);
    const float2 vb = unpack2(pkb[i]);
    const float u = (va.x + va.y) + (vb.x + vb.y);
#pragma unroll
    for (int r = 0; r < 32; ++r)
      qa[r] = fmaf(wq[i * 32 + r], u, qa[r]);
  }

  // ---- tree-reduce Q across 8 groups: 8 -> 4 -> 2 -> broadcast ----
  if (g >= 4) {
#pragma unroll
    for (int r = 0; r < 32; ++r) Qpart[(g - 4) * 2048 + r * 64 + p] = qa[r];
  }
  __syncthreads();
  if (g < 4) {
#pragma unroll
    for (int r = 0; r < 32; ++r) Qpart[g * 2048 + r * 64 + p] += qa[r];
  }
  __syncthreads();
  if (g < 2) {
#pragma unroll
    for (int r = 0; r < 32; ++r)
      Qpart[g * 2048 + r * 64 + p] += Qpart[(g + 2) * 2048 + r * 64 + p];
  }
  __syncthreads();
#pragma unroll
  for (int r = 0; r < 32; ++r)
    qa[r] = Qpart[r * 64 + p] + Qpart[2048 + r * 64 + p];

  // ---- pass 2: logits from stash (pure VALU + SMEM) ----
  float l0 = 0.f, l1 = 0.f, l2 = 0.f, l3 = 0.f;
#pragma unroll
  for (int i = 0; i < 16; ++i) {
    const float2 va = unpack2(pka[i]);
    const float2 vb = unpack2(pkb[i]);
    float t0 = 0.f, t1 = 0.f;
#pragma unroll
    for (int r = 0; r < 32; r += 2) {
      t0 = fmaf(qa[r + 0], wk[i * 32 + r + 0], t0);
      t1 = fmaf(qa[r + 1], wk[i * 32 + r + 1], t1);
    }
    const float tv = t0 + t1;
    l0 = fmaf(tv, va.x, l0);
    l1 = fmaf(tv, va.y, l1);
    l2 = fmaf(tv, vb.x, l2);
    l3 = fmaf(tv, vb.y, l3);
  }
  *(float4*)(lbuf + (g * 64 + p) * 4) = make_float4(l0, l1, l2, l3);
  __syncthreads();

  // ---- softmax (one wave combines all 8 groups, broadcasts via abuf) ----
  if (tid < 64) {
    float L0 = 0.f, L1 = 0.f, L2 = 0.f, L3 = 0.f;
#pragma unroll
    for (int k = 0; k < 8; ++k) {
      const float4 s = *(const float4*)(lbuf + (k * 64 + tid) * 4);
      L0 += s.x; L1 += s.y; L2 += s.z; L3 += s.w;
    }
    const float mx = fmaxf(fmaxf(L0, L1), fmaxf(L2, L3));
    const float e0 = __expf(L0 - mx), e1 = __expf(L1 - mx);
    const float e2 = __expf(L2 - mx), e3 = __expf(L3 - mx);
    const float inv = 1.0f / ((e0 + e1) + (e2 + e3));
    *(float4*)(abuf + tid * 4) =
        make_float4(e0 * inv, e1 * inv, e2 * inv, e3 * inv);
  }
  __syncthreads();
  const float4 at = *(const float4*)(abuf + p * 4);

  // ---- pass 3: weighted window sum from stash -> out (plain stores) ----
  {
    float* op = out + ((size_t)(b * 128 + cb) * 16384) + h * 128 + w0 + p;
#pragma unroll
    for (int i = 0; i < 16; ++i) {
      const float2 va = unpack2(pka[i]);
      const float2 vb = unpack2(pkb[i]);
      op[(size_t)i * 16384] =
          fmaf(at.x, va.x, fmaf(at.y, va.y, fmaf(at.z, vb.x, at.w * vb.y)));
    }
  }
}

extern "C" void kernel_launch(void* const* d_in, const int* in_sizes, int n_in,
                              void* d_out, int out_size, void* d_ws, size_t ws_size,
                              hipStream_t stream) {
  const float* fm = (const float*)d_in[0];
  const float* Wq = (const float*)d_in[1];
  const float* Wk = (const float*)d_in[2];
  float* outp = (float*)d_out;
  float* ws = (float*)d_ws;

  wt_kernel<<<16, 256, 0, stream>>>(Wq, Wk, ws);
  attn_main<<<2048, 512, 0, stream>>>(fm, ws, outp);
}